// Round 14
// baseline (295.061 us; speedup 1.0000x reference)
//
#include <hip/hip_runtime.h>
#include <hip/hip_bf16.h>

#define NB 4096
#define NT 50
#define NH 128
#define NINT 4
#define ROWS 64  // batch rows per block

typedef float f32x4 __attribute__((ext_vector_type(4)));
typedef __bf16 bf16x8 __attribute__((ext_vector_type(8)));
typedef short short8 __attribute__((ext_vector_type(8)));
typedef short short4s __attribute__((ext_vector_type(4)));

#define L2E 1.4426950408889634f

__device__ __forceinline__ float frcp(float x) { return __builtin_amdgcn_rcpf(x); }

// exp2(-x): v_exp_f32 computes 2^x; neg is a free src modifier.
__device__ __forceinline__ float exp2neg(float x) {
  float r;
  asm("v_exp_f32 %0, -%1" : "=v"(r) : "v"(x));
  return r;
}

__device__ __forceinline__ unsigned short bfbits(float f) {
  __bf16 b = (__bf16)f;  // native RTNE; pairs pack to v_cvt_pk_bf16_f32
  return __builtin_bit_cast(unsigned short, b);
}

// Grid: 256 blocks = NINT(4) * (NB/64).  Block: 512 threads = 8 waves, 1/CU.
// R14 = R13 + PHASE-SPLIT PING-PONG.  Evidence: R12/R13 removed large
// parallel-issue volume (LDS reads, FMAs, shuffles) for ZERO gain, while R7's
// dependent-chain cut (div->rcp) gained 42us -> the kernel is latency-bound.
// The serializer was accumulator REUSE across the 4 m-iterations: each m's
// 8-deep MFMA chain waited (WAR) for the previous m's VALU drain.  Fix: give
// every m its own acc quads (20 f32x4 = 80 AGPR), run ALL 112 MFMAs in one
// phase (A), then ALL gate math + writeback in phase (B).  The 2 waves/SIMD
// anti-phase into MFMA/VALU ping-pong (setprio(1) spans phase A).
// R9 LESSON: inline-asm v_mfma bypasses the MFMA hazard recognizer -> NaN.
// R3-R5 LESSON: weight-resident design needs the (512,2) 256-reg budget.
__global__ __launch_bounds__(512, 2)
void gru_fused(const int* __restrict__ inputs, const float* __restrict__ emb,
               const float* __restrict__ w_int, const float* __restrict__ w_ih,
               const float* __restrict__ w_hh, const float* __restrict__ b_ih,
               const float* __restrict__ b_hh, const float* __restrict__ h0,
               float* __restrict__ out) {
  __shared__ unsigned short xs[2][ROWS * NH];  // 32 KB x tile, bf16, swizzled
  __shared__ unsigned short hs[2][ROWS * NH];  // 32 KB h tile, bf16, swizzled
  __shared__ int idxs[NT * ROWS];              // 12.8 KB token ids

  const int tid = threadIdx.x;
  const int bx = blockIdx.x;
  const int I = bx >> 6;          // interest 0..3
  const int R0 = (bx & 63) * ROWS;
  const int w = tid >> 6;         // wave 0..7
  const int lane = tid & 63;
  const int l15 = lane & 15;
  const int l4 = lane >> 4;
  const int oc0 = w * 16 + l4 * 4;  // lane's first h-col (owns oc0..oc0+3)

  // staging/gather mapping: 8 threads per row, 16 floats (64B) each
  const int sr = tid >> 3;  // row 0..63
  const int sp = tid & 7;   // segment

  // ---- token indices ----
  for (int e = tid; e < NT * ROWS; e += 512) {
    int t = e >> 6, r = e & (ROWS - 1);
    idxs[e] = inputs[(size_t)(R0 + r) * NT + t];
  }
  __syncthreads();

  // ---- persistent weight fragments (96 VGPR, MFMA A-operands) + bias
  //      vectors, PRE-SCALED: gates r,i: *log2e; gate n: *2*log2e.
  //      A-frag: lane holds row(=oc_local)=lane&15, k=(lane>>4)*8 + 0..7
  bf16x8 wih[3][4], whh[3][4];
  f32x4 bR, bI, bNI, bNH;  // per-j bias vectors (j indexes oc0+j)
  {
    const float gs[3] = {L2E, L2E, 2.0f * L2E};
    #pragma unroll
    for (int g = 0; g < 3; ++g) {
      int oc = g * NH + w * 16 + l15;
      #pragma unroll
      for (int kk = 0; kk < 4; ++kk) {
        int k0 = kk * 32 + l4 * 8;
        const float* pi = w_ih + ((size_t)(I * 384 + oc) * NH + k0);
        const float* ph = w_hh + ((size_t)(I * 384 + oc) * NH + k0);
        bf16x8 si, sh;
        #pragma unroll
        for (int e = 0; e < 8; ++e) {
          si[e] = (__bf16)(pi[e] * gs[g]);
          sh[e] = (__bf16)(ph[e] * gs[g]);
        }
        wih[g][kk] = si;
        whh[g][kk] = sh;
      }
    }
    #pragma unroll
    for (int j = 0; j < 4; ++j) {
      bR[j] = (b_ih[I * 384 + oc0 + j] + b_hh[I * 384 + oc0 + j]) * L2E;
      bI[j] = (b_ih[I * 384 + NH + oc0 + j] + b_hh[I * 384 + NH + oc0 + j]) * L2E;
      bNI[j] = b_ih[I * 384 + 2 * NH + oc0 + j] * (2.0f * L2E);
      bNH[j] = b_hh[I * 384 + 2 * NH + oc0 + j] * (2.0f * L2E);
    }
  }

  // ---- w_interest A-frag (16 regs): interest i in row i (i<4), rows 4-15
  //      ZERO; scaled by 10*log2e so softmax is pure exp2 ----
  bf16x8 wg[4];
  #pragma unroll
  for (int kk = 0; kk < 4; ++kk) {
    bf16x8 f;
    #pragma unroll
    for (int e = 0; e < 8; ++e) {
      float v = (l15 < NINT)
                    ? w_int[l15 * NH + kk * 32 + l4 * 8 + e] * (10.0f * L2E)
                    : 0.0f;
      f[e] = (__bf16)v;
    }
    wg[kk] = f;
  }

  // ---- h0 master (fp32 regs) + initial bf16 LDS copy ----
  // Transposed D layout: row(batch) = m*16 + (lane&15), hcol = oc0 + j
  float hm[4][4];
  #pragma unroll
  for (int m = 0; m < 4; ++m) {
    int row = m * 16 + l15;
    short4s p;
    #pragma unroll
    for (int j = 0; j < 4; ++j) {
      float v = h0[((size_t)I * NB + R0 + row) * NH + oc0 + j];
      hm[m][j] = v;
      p[j] = (short)bfbits(v);
    }
    *(short4s*)&hs[0][(row * NH + oc0) ^ ((row & 7) << 3)] = p;
  }

  // ---- stage x(0) ----
  {
    const float4* src = (const float4*)(emb + (size_t)idxs[sr] * NH + sp * 16);
    float4 v0 = src[0], v1 = src[1], v2 = src[2], v3 = src[3];
    short8 s0, s1;
    s0[0] = bfbits(v0.x); s0[1] = bfbits(v0.y); s0[2] = bfbits(v0.z); s0[3] = bfbits(v0.w);
    s0[4] = bfbits(v1.x); s0[5] = bfbits(v1.y); s0[6] = bfbits(v1.z); s0[7] = bfbits(v1.w);
    s1[0] = bfbits(v2.x); s1[1] = bfbits(v2.y); s1[2] = bfbits(v2.z); s1[3] = bfbits(v2.w);
    s1[4] = bfbits(v3.x); s1[5] = bfbits(v3.y); s1[6] = bfbits(v3.z); s1[7] = bfbits(v3.w);
    int base = sr * NH + sp * 16;
    int sw = (sr & 7) << 3;
    *(short8*)&xs[0][base ^ sw] = s0;
    *(short8*)&xs[0][(base + 8) ^ sw] = s1;
  }
  __syncthreads();

  // ---- main recurrence ----
  for (int t = 0; t < NT; ++t) {
    const int cur = t & 1, nxt = cur ^ 1;
    const bool pf = (t + 1 < NT);

    // prefetch x(t+1) into regs; latency hides under phase A
    float4 v0, v1, v2, v3;
    if (pf) {
      const float4* src =
          (const float4*)(emb + (size_t)idxs[(t + 1) * ROWS + sr] * NH + sp * 16);
      v0 = src[0]; v1 = src[1]; v2 = src[2]; v3 = src[3];
    }

    const unsigned short* hsc = hs[cur];
    const unsigned short* xsc = xs[cur];
    unsigned short* hsn = hs[nxt];

    // per-m accumulator sets (static indices only — rule #20)
    f32x4 aG[4], aR[4], aI[4], aNI[4], aNH[4];

    // ================= PHASE A: all fragment reads + all 112 MFMAs =========
    __builtin_amdgcn_s_setprio(1);
    #pragma unroll
    for (int m = 0; m < 4; ++m) {
      aG[m] = f32x4{0.0f, 0.0f, 0.0f, 0.0f};
      aR[m] = bR; aI[m] = bI; aNI[m] = bNI; aNH[m] = bNH;
      int brow = m * 16 + l15;        // B-frag col = batch row
      int blin = brow * NH + l4 * 8;  // bits 3-4
      int sw2 = (brow & 7) << 3;      // bits 3-5
      #pragma unroll
      for (int kk = 0; kk < 4; ++kk) {
        int e = (blin + kk * 32) ^ sw2;  // kk*32: bits 5-6, carry-free; XOR full index
        bf16x8 bh = __builtin_bit_cast(bf16x8, *(const short8*)&hsc[e]);
        bf16x8 bx = __builtin_bit_cast(bf16x8, *(const short8*)&xsc[e]);
        // TRANSPOSED: A = weights, B = data -> D[oc][row]
        aG[m] = __builtin_amdgcn_mfma_f32_16x16x32_bf16(wg[kk], bx, aG[m], 0, 0, 0);
        aR[m] = __builtin_amdgcn_mfma_f32_16x16x32_bf16(wih[0][kk], bx, aR[m], 0, 0, 0);
        aR[m] = __builtin_amdgcn_mfma_f32_16x16x32_bf16(whh[0][kk], bh, aR[m], 0, 0, 0);
        aI[m] = __builtin_amdgcn_mfma_f32_16x16x32_bf16(wih[1][kk], bx, aI[m], 0, 0, 0);
        aI[m] = __builtin_amdgcn_mfma_f32_16x16x32_bf16(whh[1][kk], bh, aI[m], 0, 0, 0);
        aNI[m] = __builtin_amdgcn_mfma_f32_16x16x32_bf16(wih[2][kk], bx, aNI[m], 0, 0, 0);
        aNH[m] = __builtin_amdgcn_mfma_f32_16x16x32_bf16(whh[2][kk], bh, aNH[m], 0, 0, 0);
      }
    }
    __builtin_amdgcn_s_setprio(0);

    // ================= PHASE B: gate math + h-writeback ====================
    #pragma unroll
    for (int m = 0; m < 4; ++m) {
      int brow = m * 16 + l15;
      int sw2 = (brow & 7) << 3;

      // gate softmax from aG[m] (logits pre-scaled by 10*log2e, range |s|<~5
      // so no max-subtraction needed); broadcast row gate from lane l15
      float e0 = exp2neg(-aG[m][0]), e1 = exp2neg(-aG[m][1]);
      float e2 = exp2neg(-aG[m][2]), e3 = exp2neg(-aG[m][3]);
      float sel = (I == 0) ? e0 : (I == 1) ? e1 : (I == 2) ? e2 : e3;
      float gvl = sel * frcp(e0 + e1 + e2 + e3);
      gvl = (gvl > 0.01f) ? gvl : 0.0f;
      const float gv = __shfl(gvl, l15, 64);

      short4s p;
      #pragma unroll
      for (int j = 0; j < 4; ++j) {
        float rg = frcp(1.0f + exp2neg(aR[m][j]));
        float ig = frcp(1.0f + exp2neg(aI[m][j]));
        float an = fmaf(rg, aNH[m][j], aNI[m][j]);
        float ng = fmaf(2.0f, frcp(1.0f + exp2neg(an)), -1.0f);
        float c = gv * ig;  // gv pre-thresholded
        float hy = fmaf(c, ng - hm[m][j], hm[m][j]);
        hm[m][j] = hy;
        p[j] = (short)bfbits(hy);
      }
      // packed h-writeback: 4 consecutive h-cols, one ds_write_b64
      *(short4s*)&hsn[(brow * NH + oc0) ^ sw2] = p;
    }

    if (pf) {
      short8 s0, s1;
      s0[0] = bfbits(v0.x); s0[1] = bfbits(v0.y); s0[2] = bfbits(v0.z); s0[3] = bfbits(v0.w);
      s0[4] = bfbits(v1.x); s0[5] = bfbits(v1.y); s0[6] = bfbits(v1.z); s0[7] = bfbits(v1.w);
      s1[0] = bfbits(v2.x); s1[1] = bfbits(v2.y); s1[2] = bfbits(v2.z); s1[3] = bfbits(v2.w);
      s1[4] = bfbits(v3.x); s1[5] = bfbits(v3.y); s1[6] = bfbits(v3.z); s1[7] = bfbits(v3.w);
      int base = sr * NH + sp * 16;
      int sw = (sr & 7) << 3;
      *(short8*)&xs[nxt][base ^ sw] = s0;
      *(short8*)&xs[nxt][(base + 8) ^ sw] = s1;
    }
    __syncthreads();
  }

  // ---- epilogue: out[b][I][h], float4 per m ----
  #pragma unroll
  for (int m = 0; m < 4; ++m) {
    int row = m * 16 + l15;
    f32x4 o;
    #pragma unroll
    for (int j = 0; j < 4; ++j) o[j] = hm[m][j];
    *(f32x4*)&out[(size_t)(R0 + row) * (NINT * NH) + I * NH + oc0] = o;
  }
}

extern "C" void kernel_launch(void* const* d_in, const int* in_sizes, int n_in,
                              void* d_out, int out_size, void* d_ws, size_t ws_size,
                              hipStream_t stream) {
  const int* inputs = (const int*)d_in[0];
  const float* emb = (const float*)d_in[1];
  const float* w_int = (const float*)d_in[2];
  const float* w_ih = (const float*)d_in[3];
  const float* w_hh = (const float*)d_in[4];
  const float* b_ih = (const float*)d_in[5];
  const float* b_hh = (const float*)d_in[6];
  const float* h0 = (const float*)d_in[7];
  float* out = (float*)d_out;

  dim3 grid(NINT * (NB / ROWS));  // 256 blocks, one per CU
  dim3 block(512);
  gru_fused<<<grid, block, 0, stream>>>(inputs, emb, w_int, w_ih, w_hh, b_ih,
                                        b_hh, h0, out);
}

// Round 15
// 188.430 us; speedup vs baseline: 1.5659x; 1.5659x over previous
//
#include <hip/hip_runtime.h>
#include <hip/hip_bf16.h>

#define NB 4096
#define NT 50
#define NH 128
#define NINT 4
#define ROWS 64  // batch rows per block

typedef float f32x4 __attribute__((ext_vector_type(4)));
typedef __bf16 bf16x8 __attribute__((ext_vector_type(8)));
typedef short short8 __attribute__((ext_vector_type(8)));
typedef short short4s __attribute__((ext_vector_type(4)));

#define L2E 1.4426950408889634f

__device__ __forceinline__ float frcp(float x) { return __builtin_amdgcn_rcpf(x); }

// exp2(-x): v_exp_f32 computes 2^x; neg is a free src modifier.
__device__ __forceinline__ float exp2neg(float x) {
  float r;
  asm("v_exp_f32 %0, -%1" : "=v"(r) : "v"(x));
  return r;
}

__device__ __forceinline__ unsigned short bfbits(float f) {
  __bf16 b = (__bf16)f;  // native RTNE; pairs pack to v_cvt_pk_bf16_f32
  return __builtin_bit_cast(unsigned short, b);
}

// Grid: 256 blocks = NINT(4) * (NB/64).  Block: 512 threads = 8 waves, 1/CU.
// R15 = R13 + PAIR-WISE PHASE SPLIT (the register-feasible form of R14's
// theory).  R14's full 4-m split needed 80 acc regs -> blew the 256 budget
// (WRITE_SIZE 13->25.6MB scratch, 295us).  Pairs need 10 f32x4 = 40 regs
// (R13 was 20), halving WAR serialization depth: per step 2x[28-MFMA phase
// (10 indep chains) -> VALU phase] instead of 4x[... 5 chains ...].
// R9 LESSON: inline-asm v_mfma bypasses the MFMA hazard recognizer -> NaN.
// R3-R5 LESSON: weight-resident design needs the (512,2) 256-reg budget.
// R14 LESSON: count acc regs BEFORE adding accumulators; WRITE_SIZE is the
// spill tripwire.
__global__ __launch_bounds__(512, 2)
void gru_fused(const int* __restrict__ inputs, const float* __restrict__ emb,
               const float* __restrict__ w_int, const float* __restrict__ w_ih,
               const float* __restrict__ w_hh, const float* __restrict__ b_ih,
               const float* __restrict__ b_hh, const float* __restrict__ h0,
               float* __restrict__ out) {
  __shared__ unsigned short xs[2][ROWS * NH];  // 32 KB x tile, bf16, swizzled
  __shared__ unsigned short hs[2][ROWS * NH];  // 32 KB h tile, bf16, swizzled
  __shared__ int idxs[NT * ROWS];              // 12.8 KB token ids

  const int tid = threadIdx.x;
  const int bx = blockIdx.x;
  const int I = bx >> 6;          // interest 0..3
  const int R0 = (bx & 63) * ROWS;
  const int w = tid >> 6;         // wave 0..7
  const int lane = tid & 63;
  const int l15 = lane & 15;
  const int l4 = lane >> 4;
  const int oc0 = w * 16 + l4 * 4;  // lane's first h-col (owns oc0..oc0+3)

  // staging/gather mapping: 8 threads per row, 16 floats (64B) each
  const int sr = tid >> 3;  // row 0..63
  const int sp = tid & 7;   // segment

  // ---- token indices ----
  for (int e = tid; e < NT * ROWS; e += 512) {
    int t = e >> 6, r = e & (ROWS - 1);
    idxs[e] = inputs[(size_t)(R0 + r) * NT + t];
  }
  __syncthreads();

  // ---- persistent weight fragments (96 VGPR, MFMA A-operands) + bias
  //      vectors, PRE-SCALED: gates r,i: *log2e; gate n: *2*log2e.
  //      A-frag: lane holds row(=oc_local)=lane&15, k=(lane>>4)*8 + 0..7
  bf16x8 wih[3][4], whh[3][4];
  f32x4 bR, bI, bNI, bNH;  // per-j bias vectors (j indexes oc0+j)
  {
    const float gs[3] = {L2E, L2E, 2.0f * L2E};
    #pragma unroll
    for (int g = 0; g < 3; ++g) {
      int oc = g * NH + w * 16 + l15;
      #pragma unroll
      for (int kk = 0; kk < 4; ++kk) {
        int k0 = kk * 32 + l4 * 8;
        const float* pi = w_ih + ((size_t)(I * 384 + oc) * NH + k0);
        const float* ph = w_hh + ((size_t)(I * 384 + oc) * NH + k0);
        bf16x8 si, sh;
        #pragma unroll
        for (int e = 0; e < 8; ++e) {
          si[e] = (__bf16)(pi[e] * gs[g]);
          sh[e] = (__bf16)(ph[e] * gs[g]);
        }
        wih[g][kk] = si;
        whh[g][kk] = sh;
      }
    }
    #pragma unroll
    for (int j = 0; j < 4; ++j) {
      bR[j] = (b_ih[I * 384 + oc0 + j] + b_hh[I * 384 + oc0 + j]) * L2E;
      bI[j] = (b_ih[I * 384 + NH + oc0 + j] + b_hh[I * 384 + NH + oc0 + j]) * L2E;
      bNI[j] = b_ih[I * 384 + 2 * NH + oc0 + j] * (2.0f * L2E);
      bNH[j] = b_hh[I * 384 + 2 * NH + oc0 + j] * (2.0f * L2E);
    }
  }

  // ---- w_interest A-frag (16 regs): interest i in row i (i<4), rows 4-15
  //      ZERO; scaled by 10*log2e so softmax is pure exp2 ----
  bf16x8 wg[4];
  #pragma unroll
  for (int kk = 0; kk < 4; ++kk) {
    bf16x8 f;
    #pragma unroll
    for (int e = 0; e < 8; ++e) {
      float v = (l15 < NINT)
                    ? w_int[l15 * NH + kk * 32 + l4 * 8 + e] * (10.0f * L2E)
                    : 0.0f;
      f[e] = (__bf16)v;
    }
    wg[kk] = f;
  }

  // ---- h0 master (fp32 regs) + initial bf16 LDS copy ----
  // Transposed D layout: row(batch) = m*16 + (lane&15), hcol = oc0 + j
  float hm[4][4];
  #pragma unroll
  for (int m = 0; m < 4; ++m) {
    int row = m * 16 + l15;
    short4s p;
    #pragma unroll
    for (int j = 0; j < 4; ++j) {
      float v = h0[((size_t)I * NB + R0 + row) * NH + oc0 + j];
      hm[m][j] = v;
      p[j] = (short)bfbits(v);
    }
    *(short4s*)&hs[0][(row * NH + oc0) ^ ((row & 7) << 3)] = p;
  }

  // ---- stage x(0) ----
  {
    const float4* src = (const float4*)(emb + (size_t)idxs[sr] * NH + sp * 16);
    float4 v0 = src[0], v1 = src[1], v2 = src[2], v3 = src[3];
    short8 s0, s1;
    s0[0] = bfbits(v0.x); s0[1] = bfbits(v0.y); s0[2] = bfbits(v0.z); s0[3] = bfbits(v0.w);
    s0[4] = bfbits(v1.x); s0[5] = bfbits(v1.y); s0[6] = bfbits(v1.z); s0[7] = bfbits(v1.w);
    s1[0] = bfbits(v2.x); s1[1] = bfbits(v2.y); s1[2] = bfbits(v2.z); s1[3] = bfbits(v2.w);
    s1[4] = bfbits(v3.x); s1[5] = bfbits(v3.y); s1[6] = bfbits(v3.z); s1[7] = bfbits(v3.w);
    int base = sr * NH + sp * 16;
    int sw = (sr & 7) << 3;
    *(short8*)&xs[0][base ^ sw] = s0;
    *(short8*)&xs[0][(base + 8) ^ sw] = s1;
  }
  __syncthreads();

  // ---- main recurrence ----
  for (int t = 0; t < NT; ++t) {
    const int cur = t & 1, nxt = cur ^ 1;
    const bool pf = (t + 1 < NT);

    // prefetch x(t+1) into regs; latency hides under the MFMA phases
    float4 v0, v1, v2, v3;
    if (pf) {
      const float4* src =
          (const float4*)(emb + (size_t)idxs[(t + 1) * ROWS + sr] * NH + sp * 16);
      v0 = src[0]; v1 = src[1]; v2 = src[2]; v3 = src[3];
    }

    const unsigned short* hsc = hs[cur];
    const unsigned short* xsc = xs[cur];
    unsigned short* hsn = hs[nxt];

    #pragma unroll
    for (int mp = 0; mp < 2; ++mp) {
      // pair-local accumulators: 10 quads = 40 regs (R14's 20 quads spilled)
      f32x4 aG[2], aR[2], aI[2], aNI[2], aNH[2];

      // ---- PHASE A: both m's fragment reads + 56 MFMAs (10 indep chains) --
      __builtin_amdgcn_s_setprio(1);
      #pragma unroll
      for (int m2 = 0; m2 < 2; ++m2) {
        const int m = mp * 2 + m2;
        aG[m2] = f32x4{0.0f, 0.0f, 0.0f, 0.0f};
        aR[m2] = bR; aI[m2] = bI; aNI[m2] = bNI; aNH[m2] = bNH;
        int brow = m * 16 + l15;        // B-frag col = batch row
        int blin = brow * NH + l4 * 8;  // bits 3-4
        int sw2 = (brow & 7) << 3;      // bits 3-5
        #pragma unroll
        for (int kk = 0; kk < 4; ++kk) {
          int e = (blin + kk * 32) ^ sw2;  // carry-free add; XOR full index
          bf16x8 bh = __builtin_bit_cast(bf16x8, *(const short8*)&hsc[e]);
          bf16x8 bx = __builtin_bit_cast(bf16x8, *(const short8*)&xsc[e]);
          // TRANSPOSED: A = weights, B = data -> D[oc][row]
          aG[m2] = __builtin_amdgcn_mfma_f32_16x16x32_bf16(wg[kk], bx, aG[m2], 0, 0, 0);
          aR[m2] = __builtin_amdgcn_mfma_f32_16x16x32_bf16(wih[0][kk], bx, aR[m2], 0, 0, 0);
          aR[m2] = __builtin_amdgcn_mfma_f32_16x16x32_bf16(whh[0][kk], bh, aR[m2], 0, 0, 0);
          aI[m2] = __builtin_amdgcn_mfma_f32_16x16x32_bf16(wih[1][kk], bx, aI[m2], 0, 0, 0);
          aI[m2] = __builtin_amdgcn_mfma_f32_16x16x32_bf16(whh[1][kk], bh, aI[m2], 0, 0, 0);
          aNI[m2] = __builtin_amdgcn_mfma_f32_16x16x32_bf16(wih[2][kk], bx, aNI[m2], 0, 0, 0);
          aNH[m2] = __builtin_amdgcn_mfma_f32_16x16x32_bf16(whh[2][kk], bh, aNH[m2], 0, 0, 0);
        }
      }
      __builtin_amdgcn_s_setprio(0);

      // ---- PHASE B: both m's gate math + h-writeback ----------------------
      #pragma unroll
      for (int m2 = 0; m2 < 2; ++m2) {
        const int m = mp * 2 + m2;
        int brow = m * 16 + l15;
        int sw2 = (brow & 7) << 3;

        // gate softmax from aG (logits pre-scaled by 10*log2e, |s| small so
        // no max-subtraction); broadcast row gate from lane l15
        float e0 = exp2neg(-aG[m2][0]), e1 = exp2neg(-aG[m2][1]);
        float e2 = exp2neg(-aG[m2][2]), e3 = exp2neg(-aG[m2][3]);
        float sel = (I == 0) ? e0 : (I == 1) ? e1 : (I == 2) ? e2 : e3;
        float gvl = sel * frcp(e0 + e1 + e2 + e3);
        gvl = (gvl > 0.01f) ? gvl : 0.0f;
        const float gv = __shfl(gvl, l15, 64);

        short4s p;
        #pragma unroll
        for (int j = 0; j < 4; ++j) {
          float rg = frcp(1.0f + exp2neg(aR[m2][j]));
          float ig = frcp(1.0f + exp2neg(aI[m2][j]));
          float an = fmaf(rg, aNH[m2][j], aNI[m2][j]);
          float ng = fmaf(2.0f, frcp(1.0f + exp2neg(an)), -1.0f);
          float c = gv * ig;  // gv pre-thresholded
          float hy = fmaf(c, ng - hm[m][j], hm[m][j]);
          hm[m][j] = hy;
          p[j] = (short)bfbits(hy);
        }
        // packed h-writeback: 4 consecutive h-cols, one ds_write_b64
        *(short4s*)&hsn[(brow * NH + oc0) ^ sw2] = p;
      }
    }

    if (pf) {
      short8 s0, s1;
      s0[0] = bfbits(v0.x); s0[1] = bfbits(v0.y); s0[2] = bfbits(v0.z); s0[3] = bfbits(v0.w);
      s0[4] = bfbits(v1.x); s0[5] = bfbits(v1.y); s0[6] = bfbits(v1.z); s0[7] = bfbits(v1.w);
      s1[0] = bfbits(v2.x); s1[1] = bfbits(v2.y); s1[2] = bfbits(v2.z); s1[3] = bfbits(v2.w);
      s1[4] = bfbits(v3.x); s1[5] = bfbits(v3.y); s1[6] = bfbits(v3.z); s1[7] = bfbits(v3.w);
      int base = sr * NH + sp * 16;
      int sw = (sr & 7) << 3;
      *(short8*)&xs[nxt][base ^ sw] = s0;
      *(short8*)&xs[nxt][(base + 8) ^ sw] = s1;
    }
    __syncthreads();
  }

  // ---- epilogue: out[b][I][h], float4 per m ----
  #pragma unroll
  for (int m = 0; m < 4; ++m) {
    int row = m * 16 + l15;
    f32x4 o;
    #pragma unroll
    for (int j = 0; j < 4; ++j) o[j] = hm[m][j];
    *(f32x4*)&out[(size_t)(R0 + row) * (NINT * NH) + I * NH + oc0] = o;
  }
}

extern "C" void kernel_launch(void* const* d_in, const int* in_sizes, int n_in,
                              void* d_out, int out_size, void* d_ws, size_t ws_size,
                              hipStream_t stream) {
  const int* inputs = (const int*)d_in[0];
  const float* emb = (const float*)d_in[1];
  const float* w_int = (const float*)d_in[2];
  const float* w_ih = (const float*)d_in[3];
  const float* w_hh = (const float*)d_in[4];
  const float* b_ih = (const float*)d_in[5];
  const float* b_hh = (const float*)d_in[6];
  const float* h0 = (const float*)d_in[7];
  float* out = (float*)d_out;

  dim3 grid(NINT * (NB / ROWS));  // 256 blocks, one per CU
  dim3 block(512);
  gru_fused<<<grid, block, 0, stream>>>(inputs, emb, w_int, w_ih, w_hh, b_ih,
                                        b_hh, h0, out);
}